// Round 19
// baseline (118.099 us; speedup 1.0000x reference)
//
#include <hip/hip_runtime.h>
#include <stdint.h>

// ---------- types ----------
using short8   = __attribute__((ext_vector_type(8))) short;   // 8 x bf16 = 16B
using f32x4    = __attribute__((ext_vector_type(4))) float;
using ushort4v = __attribute__((ext_vector_type(4))) unsigned short;
using uint2v   = __attribute__((ext_vector_type(2))) unsigned int;

#define CSC  0.1803368801111f   // 0.125 * log2(e): QK^T lands in log2 units
#define FIXC 20.0f              // fixed softmax exponent offset (power-of-2: bit-exact)

#define WAITLG()   asm volatile("s_waitcnt lgkmcnt(0)" ::: "memory")
#define WAITVM(n)  asm volatile("s_waitcnt vmcnt(" #n ")" ::: "memory")
#define BAR()      __builtin_amdgcn_s_barrier()

__device__ __forceinline__ unsigned short f2bf(float f) {
    unsigned int u = __builtin_bit_cast(unsigned int, f);
    u += 0x7FFFu + ((u >> 16) & 1u);
    return (unsigned short)(u >> 16);
}
__device__ __forceinline__ float bf2f(unsigned short s) {
    unsigned int u = ((unsigned int)s) << 16;
    return __builtin_bit_cast(float, u);
}
// packed f32x2 -> bf16x2 (RNE), 1 VALU op
__device__ __forceinline__ unsigned pk2bf(float a, float b) {
    unsigned r;
    asm("v_cvt_pk_bf16_f32 %0, %1, %2" : "=v"(r) : "v"(a), "v"(b));
    return r;
}

// async global->LDS, 16B per lane. LDS dest = wave-uniform base + lane*16.
__device__ __forceinline__ void gload16(const void* g, void* l) {
    __builtin_amdgcn_global_load_lds(
        (const __attribute__((address_space(1))) void*)(uintptr_t)g,
        (__attribute__((address_space(3))) void*)(unsigned)(uintptr_t)l,
        16, 0, 0);
}

// ---------- shared LN row body (one wave, 256-wide row), result packed bf16x4 ----------
__device__ __forceinline__ uint2v ln_row_pk(f32x4 v, f32x4 gv, f32x4 bvv) {
    float s  = v[0] + v[1] + v[2] + v[3];
    float s2 = v[0]*v[0] + v[1]*v[1] + v[2]*v[2] + v[3]*v[3];
    for (int m = 1; m < 64; m <<= 1) {
        s  += __shfl_xor(s,  m, 64);
        s2 += __shfl_xor(s2, m, 64);
    }
    float mu  = s * (1.0f / 256.0f);
    float var = s2 * (1.0f / 256.0f) - mu * mu;
    float rs  = rsqrtf(var + 1e-5f);
    float r0 = (v[0] - mu) * rs * gv[0] + bvv[0];
    float r1 = (v[1] - mu) * rs * gv[1] + bvv[1];
    float r2 = (v[2] - mu) * rs * gv[2] + bvv[2];
    float r3 = (v[3] - mu) * rs * gv[3] + bvv[3];
    uint2v u; u[0] = pk2bf(r0, r1); u[1] = pk2bf(r2, r3);
    return u;
}

// ---------- prep: weight transposes (blocks 0..191) + LN1 (blocks 192..6335) ----------
__global__ __launch_bounds__(256) void prep_k(const float* __restrict__ x, const float* __restrict__ g1,
                                              const float* __restrict__ be1, unsigned short* __restrict__ h,
                                              const float* __restrict__ Wq, const float* __restrict__ Wk,
                                              const float* __restrict__ Wv, const float* __restrict__ Wo,
                                              const float* __restrict__ W1, const float* __restrict__ W2,
                                              unsigned short* __restrict__ wpackT, unsigned short* __restrict__ woT,
                                              unsigned short* __restrict__ w1T, unsigned short* __restrict__ w2T) {
    __shared__ float t[64][65];
    if (blockIdx.x >= 192) {
        int row  = (blockIdx.x - 192) * 4 + (threadIdx.x >> 6);
        int lane = threadIdx.x & 63;
        f32x4 v = *(const f32x4*)(x + (size_t)row * 256 + lane * 4);
        f32x4 gv = *(const f32x4*)(g1 + lane * 4);
        f32x4 bv = *(const f32x4*)(be1 + lane * 4);
        uint2v u = ln_row_pk(v, gv, bv);
        *(uint2v*)(h + (size_t)row * 256 + lane * 4) = u;
        return;
    }
    const int bid = blockIdx.x;
    const float* in; unsigned short* out;
    int R, C, r0, c0;
    if (bid < 48) {
        int z = bid >> 2, cx = bid & 3;
        int qkv = z >> 2, hh = z & 3;
        in = ((qkv == 0) ? Wq : (qkv == 1) ? Wk : Wv) + (size_t)hh * 256 * 64;
        out = wpackT + (size_t)(qkv * 256 + hh * 64) * 256;
        R = 256; C = 64; r0 = cx * 64; c0 = 0;
    } else if (bid < 64) {
        int tt = bid - 48;
        in = Wo; out = woT; R = 256; C = 256; r0 = (tt >> 2) * 64; c0 = (tt & 3) * 64;
    } else if (bid < 128) {
        int tt = bid - 64;
        in = W1; out = w1T; R = 256; C = 1024; r0 = (tt & 3) * 64; c0 = (tt >> 2) * 64;
    } else {
        int tt = bid - 128;
        in = W2; out = w2T; R = 1024; C = 256; r0 = (tt & 15) * 64; c0 = (tt >> 4) * 64;
    }
    const int tx = threadIdx.x & 63, ty = threadIdx.x >> 6;
    #pragma unroll
    for (int i = 0; i < 64; i += 4)
        t[i + ty][tx] = in[(size_t)(r0 + i + ty) * C + c0 + tx];
    __syncthreads();
    #pragma unroll
    for (int i = 0; i < 64; i += 4)
        out[(size_t)(c0 + i + ty) * R + r0 + tx] = f2bf(t[tx][i + ty]);
}

// ---------- merged QK + V^T GEMM (1152 blocks), XCD-grouped, FULL-K staging ----------
// All 4 K-steps staged up front (32 gloads/thread, 128KB LDS), ONE barrier drain,
// then straight-line 128-MFMA compute with zero further barriers.
__global__ __launch_bounds__(256) void qkv_k(const unsigned short* __restrict__ h,
                                             const unsigned short* __restrict__ wpackT,
                                             unsigned short* __restrict__ qk,
                                             unsigned short* __restrict__ vT) {
    __shared__ unsigned short As[4][128 * 64];   // 64KB
    __shared__ unsigned short Bs[4][128 * 64];   // 64KB
    const int tid  = threadIdx.x;
    const int lane = tid & 63;
    const int w    = tid >> 6;
    const int wm   = w >> 1, wn = w & 1;
    const int l15  = lane & 15, l4 = lane >> 4;
    const int bid  = blockIdx.x;

    const unsigned short *A, *BT;
    unsigned short* outp;
    int bm, bn, N;
    float qsc = 1.0f;
    if (bid < 768) {
        const int xcd = bid & 7, i = bid >> 3;
        bm = xcd * 24 + (i >> 2);
        bn = i & 3;
        A = h; BT = wpackT; outp = qk; N = 512;
        if (bn < 2) qsc = CSC;
    } else {
        const int t = bid - 768;
        const int xcd = t & 7, j = t >> 3;
        bn = xcd * 24 + (j >> 1);
        bm = j & 1;
        A = wpackT + 512 * 256; BT = h; outp = vT; N = 24576;
    }
    const int K = 256;

    f32x4 acc[4][4] = {};

    const size_t K2 = (size_t)K * 2;
    const int i0   = w * 4096 + lane * 16;
    const int row0 = i0 >> 7;
    const int cb0  = (i0 & 127) ^ ((row0 & 7) << 4);
    const char* aSrc = (const char*)A  + ((size_t)(bm * 128 + row0)) * K2 + cb0;
    const char* bSrc = (const char*)BT + ((size_t)(bn * 128 + row0)) * K2 + cb0;

    // stage ALL K-steps (32 outstanding loads/thread), single drain
    #pragma unroll
    for (int t = 0; t < 4; ++t) {
        #pragma unroll
        for (int c = 0; c < 4; ++c) {
            gload16(aSrc + (size_t)t * 128 + (size_t)c * 8 * K2,
                    (char*)&As[t][0] + w * 4096 + c * 1024);
            gload16(bSrc + (size_t)t * 128 + (size_t)c * 8 * K2,
                    (char*)&Bs[t][0] + w * 4096 + c * 1024);
        }
    }
    __syncthreads();   // the only barrier: all panels resident

    #pragma unroll
    for (int t = 0; t < 4; ++t) {
        #pragma unroll
        for (int kf = 0; kf < 2; ++kf) {
            int kb = kf * 64 + l4 * 16;
            short8 af[4], bfr[4];
            #pragma unroll
            for (int mf = 0; mf < 4; ++mf) {
                int row = wm * 64 + mf * 16 + l15;
                af[mf] = *(const short8*)((const char*)&As[t][0] + ((row * 128 + kb) ^ ((row & 7) << 4)));
            }
            #pragma unroll
            for (int nf = 0; nf < 4; ++nf) {
                int row = wn * 64 + nf * 16 + l15;
                bfr[nf] = *(const short8*)((const char*)&Bs[t][0] + ((row * 128 + kb) ^ ((row & 7) << 4)));
            }
            #pragma unroll
            for (int mf = 0; mf < 4; ++mf)
                #pragma unroll
                for (int nf = 0; nf < 4; ++nf)
                    acc[mf][nf] = __builtin_amdgcn_mfma_f32_16x16x32_bf16(af[mf], bfr[nf], acc[mf][nf], 0, 0, 0);
        }
    }

    #pragma unroll
    for (int nf = 0; nf < 4; ++nf) {
        int col = bn * 128 + wn * 64 + nf * 16 + l15;
        #pragma unroll
        for (int mf = 0; mf < 4; ++mf) {
            int row0o = bm * 128 + wm * 64 + mf * 16 + l4 * 4;
            size_t off = (size_t)row0o * N + col;
            unsigned p01 = pk2bf(acc[mf][nf][0] * qsc, acc[mf][nf][1] * qsc);
            unsigned p23 = pk2bf(acc[mf][nf][2] * qsc, acc[mf][nf][3] * qsc);
            outp[off]                 = (unsigned short)p01;
            outp[off + (size_t)N]     = (unsigned short)(p01 >> 16);
            outp[off + (size_t)N * 2] = (unsigned short)p23;
            outp[off + (size_t)N * 3] = (unsigned short)(p23 >> 16);
        }
    }
}

// ---------- O-proj GEMM, FULL-K staging (K=256): x1 = o@Wo + bo + resid(f32) -> bf16 ----------
__global__ __launch_bounds__(256) void oproj_k(const unsigned short* __restrict__ A,
                                               const unsigned short* __restrict__ BT,
                                               unsigned short* __restrict__ outp,
                                               const float* __restrict__ bias,
                                               const float* __restrict__ resid) {
    __shared__ unsigned short As[4][128 * 64];
    __shared__ unsigned short Bs[4][128 * 64];
    const int tid  = threadIdx.x;
    const int lane = tid & 63;
    const int w    = tid >> 6;
    const int wm   = w >> 1, wn = w & 1;
    const int bm   = blockIdx.y, bn = blockIdx.x;
    const int l15  = lane & 15, l4 = lane >> 4;
    const int N = 256;

    f32x4 acc[4][4] = {};

    const size_t K2 = 512;
    const int i0   = w * 4096 + lane * 16;
    const int row0 = i0 >> 7;
    const int cb0  = (i0 & 127) ^ ((row0 & 7) << 4);
    const char* aSrc = (const char*)A  + ((size_t)(bm * 128 + row0)) * K2 + cb0;
    const char* bSrc = (const char*)BT + ((size_t)(bn * 128 + row0)) * K2 + cb0;

    #pragma unroll
    for (int t = 0; t < 4; ++t) {
        #pragma unroll
        for (int c = 0; c < 4; ++c) {
            gload16(aSrc + (size_t)t * 128 + (size_t)c * 8 * K2,
                    (char*)&As[t][0] + w * 4096 + c * 1024);
            gload16(bSrc + (size_t)t * 128 + (size_t)c * 8 * K2,
                    (char*)&Bs[t][0] + w * 4096 + c * 1024);
        }
    }
    __syncthreads();

    #pragma unroll
    for (int t = 0; t < 4; ++t) {
        #pragma unroll
        for (int kf = 0; kf < 2; ++kf) {
            int kb = kf * 64 + l4 * 16;
            short8 af[4], bfr[4];
            #pragma unroll
            for (int mf = 0; mf < 4; ++mf) {
                int row = wm * 64 + mf * 16 + l15;
                af[mf] = *(const short8*)((const char*)&As[t][0] + ((row * 128 + kb) ^ ((row & 7) << 4)));
            }
            #pragma unroll
            for (int nf = 0; nf < 4; ++nf) {
                int row = wn * 64 + nf * 16 + l15;
                bfr[nf] = *(const short8*)((const char*)&Bs[t][0] + ((row * 128 + kb) ^ ((row & 7) << 4)));
            }
            #pragma unroll
            for (int mf = 0; mf < 4; ++mf)
                #pragma unroll
                for (int nf = 0; nf < 4; ++nf)
                    acc[mf][nf] = __builtin_amdgcn_mfma_f32_16x16x32_bf16(af[mf], bfr[nf], acc[mf][nf], 0, 0, 0);
        }
    }

    #pragma unroll
    for (int nf = 0; nf < 4; ++nf) {
        int col = bn * 128 + wn * 64 + nf * 16 + l15;
        float bv = bias[col];
        #pragma unroll
        for (int mf = 0; mf < 4; ++mf) {
            int row0o = bm * 128 + wm * 64 + mf * 16 + l4 * 4;
            size_t off = (size_t)row0o * N + col;
            float v[4];
            #pragma unroll
            for (int r = 0; r < 4; ++r)
                v[r] = acc[mf][nf][r] + bv + resid[off + (size_t)r * N];
            unsigned p01 = pk2bf(v[0], v[1]), p23 = pk2bf(v[2], v[3]);
            outp[off]                 = (unsigned short)p01;
            outp[off + (size_t)N]     = (unsigned short)(p01 >> 16);
            outp[off + (size_t)N * 2] = (unsigned short)p23;
            outp[off + (size_t)N * 3] = (unsigned short)(p23 >> 16);
        }
    }
}

// ---------- fused LN2 + FF v8 (R18-proven, FROZEN): counted-vmcnt pipeline ----------
__global__ __launch_bounds__(256) void ff_fused(const unsigned short* __restrict__ x1b,
                                                const float* __restrict__ g2,
                                                const float* __restrict__ be2,
                                                const unsigned short* __restrict__ w1T,
                                                const unsigned short* __restrict__ w2T,
                                                const float* __restrict__ b1,
                                                const float* __restrict__ b2,
                                                float* __restrict__ out) {
    __shared__ __align__(16) char smem[147456];
    const int tid = threadIdx.x, lane = tid & 63, w = tid >> 6;
    const int l15 = lane & 15, l4 = lane >> 4;
    const int wm = w >> 1, wn = w & 1;
    const int r0 = blockIdx.x * 96;

    // ---- LN2 prologue: 96 rows -> sA (overlaying smem[0,48K)), subtile+swizzle ----
    {
        f32x4 gv = *(const f32x4*)(g2 + lane * 4);
        f32x4 bv = *(const f32x4*)(be2 + lane * 4);
        const int ks = lane >> 4, colb = (lane & 15) * 8;
        #pragma unroll
        for (int it = 0; it < 24; ++it) {
            int row = it * 4 + w;
            ushort4v u4 = *(const ushort4v*)(x1b + (size_t)(r0 + row) * 256 + lane * 4);
            f32x4 v;
            #pragma unroll
            for (int q = 0; q < 4; ++q) v[q] = bf2f(u4[q]);
            uint2v u = ln_row_pk(v, gv, bv);
            *(uint2v*)(smem + ks * 12288 + row * 128 + (colb ^ ((row & 7) << 4))) = u;
        }
    }
    WAITLG(); BAR();                 // LN2 writes visible to all waves

    // ---- hoist A-fragments to registers ----
    short8 hfr[3][4][2];             // [mf][ks][kf] — fully static indexing
    #pragma unroll
    for (int mf = 0; mf < 3; ++mf) {
        const int row = wm * 48 + mf * 16 + l15;
        #pragma unroll
        for (int ks = 0; ks < 4; ++ks)
            #pragma unroll
            for (int kf = 0; kf < 2; ++kf) {
                const int kb = kf * 64 + l4 * 16;
                hfr[mf][ks][kf] = *(const short8*)(smem + ks * 12288
                                    + ((row * 128 + kb) ^ ((row & 7) << 4)));
            }
    }
    WAITLG(); BAR();                 // all hoist reads done -> sA space reusable

    auto stage_w1 = [&](int c, int buf) {
        const char* wb = (const char*)w1T + (size_t)(c * 64) * 512;
        #pragma unroll
        for (int g = 0; g < 8; ++g) {
            int j = g * 4096 + tid * 16;
            int ks = j >> 13, row = (j >> 7) & 63, cb = j & 127;
            gload16(wb + (size_t)row * 512 + ks * 128 + (cb ^ ((row & 7) << 4)),
                    smem + buf * 32768 + j);
        }
    };
    auto stage_w2 = [&](int c, int buf) {
        const char* wb = (const char*)w2T + (size_t)c * 128;
        #pragma unroll
        for (int g = 0; g < 8; ++g) {
            int j = g * 4096 + tid * 16;
            int row = j >> 7, cb = j & 127;
            gload16(wb + (size_t)row * 2048 + (cb ^ ((row & 7) << 4)),
                    smem + 65536 + buf * 32768 + j);
        }
    };

    gload16((const char*)b1 + tid * 16, smem + 143360 + tid * 16);
    stage_w1(0, 0);
    stage_w2(0, 0);
    stage_w1(1, 1);

    const float* sB1f = (const float*)(smem + 143360);
    f32x4 oacc[3][8] = {};           // wave = 48 rows (wm) x 128 cols (wn)

    for (int c = 0; c < 16; ++c) {
        WAITLG();
        if (c < 15) { WAITVM(16); } else { WAITVM(8); }
        BAR();
        if (c + 1 < 16) stage_w2(c + 1, (c + 1) & 1);

        const char* W1B = smem + (c & 1) * 32768;
        f32x4 aacc[3][2] = {};
        __builtin_amdgcn_s_setprio(1);
        #pragma unroll
        for (int ks = 0; ks < 4; ++ks) {
            #pragma unroll
            for (int kf = 0; kf < 2; ++kf) {
                const int kb = kf * 64 + l4 * 16;
                short8 wf[2];
                #pragma unroll
                for (int nf = 0; nf < 2; ++nf) {
                    int row = wn * 32 + nf * 16 + l15;
                    wf[nf] = *(const short8*)(W1B + ks * 8192
                               + ((row * 128 + kb) ^ ((row & 7) << 4)));
                }
                #pragma unroll
                for (int mf = 0; mf < 3; ++mf)
                    #pragma unroll
                    for (int nf = 0; nf < 2; ++nf)
                        aacc[mf][nf] = __builtin_amdgcn_mfma_f32_16x16x32_bf16(wf[nf], hfr[mf][ks][kf], aacc[mf][nf], 0, 0, 0);
            }
        }
        __builtin_amdgcn_s_setprio(0);
        #pragma unroll
        for (int mf = 0; mf < 3; ++mf)
            #pragma unroll
            for (int nf = 0; nf < 2; ++nf) {
                int nl = wn * 32 + nf * 16 + l4 * 4;
                f32x4 bv = *(const f32x4*)(sB1f + c * 64 + nl);
                float v0 = aacc[mf][nf][0] + bv[0]; v0 = v0 > 0.0f ? v0 : 0.0f;
                float v1 = aacc[mf][nf][1] + bv[1]; v1 = v1 > 0.0f ? v1 : 0.0f;
                float v2 = aacc[mf][nf][2] + bv[2]; v2 = v2 > 0.0f ? v2 : 0.0f;
                float v3 = aacc[mf][nf][3] + bv[3]; v3 = v3 > 0.0f ? v3 : 0.0f;
                uint2v u; u[0] = pk2bf(v0, v1); u[1] = pk2bf(v2, v3);
                int m = wm * 48 + mf * 16 + l15;
                *(uint2v*)(smem + 131072 + ((m * 128 + nl * 2) ^ ((m & 7) << 4))) = u;
            }

        WAITLG();
        if (c < 15) { WAITVM(16); } else { WAITVM(0); }
        BAR();
        if (c + 2 < 16) stage_w1(c + 2, c & 1);

        const char* W2B = smem + 65536 + (c & 1) * 32768;
        __builtin_amdgcn_s_setprio(1);
        #pragma unroll
        for (int kf = 0; kf < 2; ++kf) {
            const int kb = kf * 64 + l4 * 16;
            short8 af[3], wf[8];
            #pragma unroll
            for (int mf = 0; mf < 3; ++mf) {
                int m = wm * 48 + mf * 16 + l15;
                af[mf] = *(const short8*)(smem + 131072 + ((m * 128 + kb) ^ ((m & 7) << 4)));
            }
            #pragma unroll
            for (int nf = 0; nf < 8; ++nf) {
                int n2 = wn * 128 + nf * 16 + l15;
                wf[nf] = *(const short8*)(W2B + ((n2 * 128 + kb) ^ ((n2 & 7) << 4)));
            }
            #pragma unroll
            for (int mf = 0; mf < 3; ++mf)
                #pragma unroll
                for (int nf = 0; nf < 8; ++nf)
                    oacc[mf][nf] = __builtin_amdgcn_mfma_f32_16x16x32_bf16(af[mf], wf[nf], oacc[mf][nf], 0, 0, 0);
        }
        __builtin_amdgcn_s_setprio(0);
    }

    #pragma unroll
    for (int nf = 0; nf < 8; ++nf) {
        const int col = wn * 128 + nf * 16 + l15;
        const float bv = b2[col];
        #pragma unroll
        for (int mf = 0; mf < 3; ++mf) {
            const int row = r0 + wm * 48 + mf * 16 + l4 * 4;
            const size_t off = (size_t)row * 256 + col;
            #pragma unroll
            for (int r = 0; r < 4; ++r)
                out[off + (size_t)r * 256] = oacc[mf][nf][r] + bv + bf2f(x1b[off + (size_t)r * 256]);
        }
    }
}

// ---------- fused causal attention (R6-proven) ----------
__global__ __launch_bounds__(256) void attn_k(const unsigned short* __restrict__ qk,
                                              const unsigned short* __restrict__ vT,
                                              unsigned short* __restrict__ o) {
    __shared__ unsigned short Ks[2][64 * 64];
    __shared__ unsigned short Vt[2][64 * 64];
    __shared__ unsigned short Pl[4][16 * 64];
    const int tid = threadIdx.x, lane = tid & 63, w = tid >> 6;
    const int l15 = lane & 15, l4 = lane >> 4;
    const int gid = blockIdx.x;
    const int xcd = gid & 7, slot = gid >> 3;
    const int sl6 = slot / 6;
    const int bh  = xcd * 16 + sl6;
    const int x   = slot - sl6 * 6;
    const int qb1 = x, qb2 = 11 - x;
    const int b = bh >> 2, h = bh & 3;
    const unsigned short* Qb = qk + (size_t)b * 768 * 512 + h * 64;
    const char* Kg = (const char*)(Qb + 256);
    const char* Vg = (const char*)(vT + (size_t)(h * 64) * 24576 + (size_t)b * 768);
    const int t01 = qb1 * 64, t02 = qb2 * 64;
    const int tq1 = t01 + w * 16 + l15;
    const int tq2 = t02 + w * 16 + l15;

    short8 q1f0 = *(const short8*)(Qb + (size_t)tq1 * 512 + l4 * 8);
    short8 q1f1 = *(const short8*)(Qb + (size_t)tq1 * 512 + 32 + l4 * 8);
    short8 q2f0 = *(const short8*)(Qb + (size_t)tq2 * 512 + l4 * 8);
    short8 q2f1 = *(const short8*)(Qb + (size_t)tq2 * 512 + 32 + l4 * 8);

    const int srow = w * 16 + (lane >> 3);
    const int scb  = ((lane & 7) * 16) ^ ((srow & 7) << 4);
    const char* kSrc = Kg + (size_t)srow * 1024 + scb;
    const char* vSrc = Vg + (size_t)srow * 49152 + scb;
    char* kDst0 = (char*)&Ks[0][0] + w * 2048;
    char* vDst0 = (char*)&Vt[0][0] + w * 2048;

    f32x4 oA[4] = {}, oB[4] = {};
    float lsA = 0.0f, lsB = 0.0f;
    unsigned short* Pw = &Pl[w][0];
    const char* KsB;
    const char* VtB;
    int sb = 0;

    auto do_tile = [&](short8 qf0, short8 qf1, f32x4 (&oacc)[4], float& lsum, bool diag, int tq) {
        f32x4 sacc[4] = {};
        __builtin_amdgcn_s_setprio(1);
        #pragma unroll
        for (int kf = 0; kf < 2; ++kf) {
            const int kb = kf * 64 + l4 * 16;
            short8 qf = kf ? qf1 : qf0;
            #pragma unroll
            for (int nf = 0; nf < 4; ++nf) {
                int sr = nf * 16 + l15;
                short8 kfr = *(const short8*)(KsB + ((sr * 128 + kb) ^ ((sr & 7) << 4)));
                sacc[nf] = __builtin_amdgcn_mfma_f32_16x16x32_bf16(kfr, qf, sacc[nf], 0, 0, 0);
            }
        }
        __builtin_amdgcn_s_setprio(0);

        if (diag) {
            #pragma unroll
            for (int nf = 0; nf < 4; ++nf)
                #pragma unroll
                for (int r = 0; r < 4; ++r) {
                    int s = sb * 64 + nf * 16 + l4 * 4 + r;
                    if (s > tq) sacc[nf][r] = -1e30f;
                }
        }
        float psum = 0.0f;
        #pragma unroll
        for (int nf = 0; nf < 4; ++nf) {
            float p0 = __builtin_amdgcn_exp2f(sacc[nf][0] - FIXC);
            float p1 = __builtin_amdgcn_exp2f(sacc[nf][1] - FIXC);
            float p2 = __builtin_amdgcn_exp2f(sacc[nf][2] - FIXC);
            float p3 = __builtin_amdgcn_exp2f(sacc[nf][3] - FIXC);
            psum += (p0 + p1) + (p2 + p3);
            uint2v u; u[0] = pk2bf(p0, p1); u[1] = pk2bf(p2, p3);
            *(uint2v*)((char*)Pw + ((l15 * 128 + nf * 32 + l4 * 8) ^ ((l15 & 7) << 4))) = u;
        }
        psum += __shfl_xor(psum, 16, 64);
        psum += __shfl_xor(psum, 32, 64);
        lsum += psum;

        __builtin_amdgcn_s_setprio(1);
        #pragma unroll
        for (int kf = 0; kf < 2; ++kf) {
            const int kb = kf * 64 + l4 * 16;
            short8 pa = *(const short8*)((const char*)Pw + ((l15 * 128 + kb) ^ ((l15 & 7) << 4)));
            #pragma unroll
            for (int nf = 0; nf < 4; ++nf) {
                int dr = nf * 16 + l15;
                short8 vfr = *(const short8*)(VtB + ((dr * 128 + kb) ^ ((dr & 7) << 4)));
                oacc[nf] = __builtin_amdgcn_mfma_f32_16x16x32_bf16(pa, vfr, oacc[nf], 0, 0, 0);
            }
        }
        __builtin_amdgcn_s_setprio(0);
    };

    gload16(kSrc, kDst0);                 gload16(kSrc + 8 * 1024, kDst0 + 1024);
    gload16(vSrc, vDst0);                 gload16(vSrc + 8 * 49152, vDst0 + 1024);

    for (sb = 0; sb <= qb2; ++sb) {
        const int pb = sb & 1;
        __syncthreads();
        if (sb < qb2) {
            const char* ks = kSrc + (size_t)(sb + 1) * 65536;
            const char* vs = vSrc + (size_t)(sb + 1) * 128;
            char* kd = kDst0 + (pb ^ 1) * 8192;
            char* vd = vDst0 + (pb ^ 1) * 8192;
            gload16(ks, kd);              gload16(ks + 8 * 1024, kd + 1024);
            gload16(vs, vd);              gload16(vs + 8 * 49152, vd + 1024);
        }
        KsB = (const char*)&Ks[0][0] + pb * 8192;
        VtB = (const char*)&Vt[0][0] + pb * 8192;

        do_tile(q2f0, q2f1, oB, lsB, sb == qb2, tq2);
        if (sb <= qb1) do_tile(q1f0, q1f1, oA, lsA, sb == qb1, tq1);
    }

    float liA = 1.0f / lsA, liB = 1.0f / lsB;
    float lrA[4], lrB[4];
    #pragma unroll
    for (int r = 0; r < 4; ++r) {
        lrA[r] = __shfl(liA, l4 * 4 + r, 64);
        lrB[r] = __shfl(liB, l4 * 4 + r, 64);
    }
    const int tA = t01 + w * 16 + l4 * 4;
    const int tB = t02 + w * 16 + l4 * 4;
    unsigned short* oa = o + ((size_t)(b * 768 + tA)) * 256 + h * 64;
    unsigned short* ob = o + ((size_t)(b * 768 + tB)) * 256 + h * 64;
    #pragma unroll
    for (int nf = 0; nf < 4; ++nf) {
        unsigned a01 = pk2bf(oA[nf][0] * lrA[0], oA[nf][1] * lrA[1]);
        unsigned a23 = pk2bf(oA[nf][2] * lrA[2], oA[nf][3] * lrA[3]);
        unsigned b01 = pk2bf(oB[nf][0] * lrB[0], oB[nf][1] * lrB[1]);
        unsigned b23 = pk2bf(oB[nf][2] * lrB[2], oB[nf][3] * lrB[3]);
        oa[nf * 16 + l15]       = (unsigned short)a01;
        oa[256 + nf * 16 + l15] = (unsigned short)(a01 >> 16);
        oa[512 + nf * 16 + l15] = (unsigned short)a23;
        oa[768 + nf * 16 + l15] = (unsigned short)(a23 >> 16);
        ob[nf * 16 + l15]       = (unsigned short)b01;
        ob[256 + nf * 16 + l15] = (unsigned short)(b01 >> 16);
        ob[512 + nf * 16 + l15] = (unsigned short)b23;
        ob[768 + nf * 16 + l15] = (unsigned short)(b23 >> 16);
    }
}

// ---------- launch ----------
extern "C" void kernel_launch(void* const* d_in, const int* in_sizes, int n_in,
                              void* d_out, int out_size, void* d_ws, size_t ws_size,
                              hipStream_t stream) {
    const float* x   = (const float*)d_in[0];
    const float* Wq  = (const float*)d_in[1];
    const float* Wk  = (const float*)d_in[2];
    const float* Wv  = (const float*)d_in[3];
    const float* Wo  = (const float*)d_in[4];
    const float* bo  = (const float*)d_in[5];
    const float* W1  = (const float*)d_in[6];
    const float* b1  = (const float*)d_in[7];
    const float* W2  = (const float*)d_in[8];
    const float* b2  = (const float*)d_in[9];
    const float* g1  = (const float*)d_in[10];
    const float* be1 = (const float*)d_in[11];
    const float* g2  = (const float*)d_in[12];
    const float* be2 = (const float*)d_in[13];

    char* ws = (char*)d_ws;
    unsigned short* qk_ws  = (unsigned short*)(ws + 0);          // 24576x512 bf16
    unsigned short* vT_ws  = (unsigned short*)(ws + 25165824);   // 256x24576 bf16
    unsigned short* o_ws   = (unsigned short*)(ws + 37748736);   // 24576x256 bf16
    unsigned short* h_ws   = (unsigned short*)(ws + 50331648);   // 24576x256 bf16 (LN1 out)
    unsigned short* x1b_ws = (unsigned short*)(ws + 62914560);   // 24576x256 bf16 residual
    unsigned short* wpackT = (unsigned short*)(ws + 88080384);   // 768x256 bf16
    unsigned short* woT    = (unsigned short*)(ws + 88473600);   // 256x256
    unsigned short* w1T    = (unsigned short*)(ws + 88604672);   // 1024x256
    unsigned short* w2T    = (unsigned short*)(ws + 89128960);   // 256x1024

    // transposes (192 blocks) + LN1 (6144 blocks)
    prep_k<<<6336, 256, 0, stream>>>(x, g1, be1, h_ws, Wq, Wk, Wv, Wo, W1, W2, wpackT, woT, w1T, w2T);
    // merged: QK [24576x512] (Q pre-scaled) + V^T [256x24576], XCD-grouped, full-K staged
    qkv_k<<<1152, 256, 0, stream>>>(h_ws, wpackT, qk_ws, vT_ws);
    attn_k<<<768, 256, 0, stream>>>(qk_ws, vT_ws, o_ws);
    // O-proj + bo + resid(x, f32) -> x1 (bf16), full-K staged
    oproj_k<<<dim3(2, 192), 256, 0, stream>>>(o_ws, woT, x1b_ws, bo, x);
    // fused LN2 + FF v8 (counted-vmcnt pipeline, frozen): out = x1 + ReLU(LN2(x1)@W1+b1)@W2 + b2
    ff_fused<<<256, 256, 0, stream>>>(x1b_ws, g2, be2, w1T, w2T, b1, b2, (float*)d_out);
}

// Round 20
// 108.884 us; speedup vs baseline: 1.0846x; 1.0846x over previous
//
#include <hip/hip_runtime.h>
#include <stdint.h>

// ---------- types ----------
using short8   = __attribute__((ext_vector_type(8))) short;   // 8 x bf16 = 16B
using f32x4    = __attribute__((ext_vector_type(4))) float;
using ushort4v = __attribute__((ext_vector_type(4))) unsigned short;
using uint2v   = __attribute__((ext_vector_type(2))) unsigned int;

#define CSC  0.1803368801111f   // 0.125 * log2(e): QK^T lands in log2 units
#define FIXC 20.0f              // fixed softmax exponent offset (power-of-2: bit-exact)

#define WAITLG()   asm volatile("s_waitcnt lgkmcnt(0)" ::: "memory")
#define WAITVM(n)  asm volatile("s_waitcnt vmcnt(" #n ")" ::: "memory")
#define BAR()      __builtin_amdgcn_s_barrier()

__device__ __forceinline__ unsigned short f2bf(float f) {
    unsigned int u = __builtin_bit_cast(unsigned int, f);
    u += 0x7FFFu + ((u >> 16) & 1u);
    return (unsigned short)(u >> 16);
}
__device__ __forceinline__ float bf2f(unsigned short s) {
    unsigned int u = ((unsigned int)s) << 16;
    return __builtin_bit_cast(float, u);
}
// packed f32x2 -> bf16x2 (RNE), 1 VALU op
__device__ __forceinline__ unsigned pk2bf(float a, float b) {
    unsigned r;
    asm("v_cvt_pk_bf16_f32 %0, %1, %2" : "=v"(r) : "v"(a), "v"(b));
    return r;
}

// async global->LDS, 16B per lane. LDS dest = wave-uniform base + lane*16.
__device__ __forceinline__ void gload16(const void* g, void* l) {
    __builtin_amdgcn_global_load_lds(
        (const __attribute__((address_space(1))) void*)(uintptr_t)g,
        (__attribute__((address_space(3))) void*)(unsigned)(uintptr_t)l,
        16, 0, 0);
}

// ---------- shared LN row body (one wave, 256-wide row), result packed bf16x4 ----------
__device__ __forceinline__ uint2v ln_row_pk(f32x4 v, f32x4 gv, f32x4 bvv) {
    float s  = v[0] + v[1] + v[2] + v[3];
    float s2 = v[0]*v[0] + v[1]*v[1] + v[2]*v[2] + v[3]*v[3];
    for (int m = 1; m < 64; m <<= 1) {
        s  += __shfl_xor(s,  m, 64);
        s2 += __shfl_xor(s2, m, 64);
    }
    float mu  = s * (1.0f / 256.0f);
    float var = s2 * (1.0f / 256.0f) - mu * mu;
    float rs  = rsqrtf(var + 1e-5f);
    float r0 = (v[0] - mu) * rs * gv[0] + bvv[0];
    float r1 = (v[1] - mu) * rs * gv[1] + bvv[1];
    float r2 = (v[2] - mu) * rs * gv[2] + bvv[2];
    float r3 = (v[3] - mu) * rs * gv[3] + bvv[3];
    uint2v u; u[0] = pk2bf(r0, r1); u[1] = pk2bf(r2, r3);
    return u;
}

// ---------- prep: weight transposes (blocks 0..191) + LN1 (blocks 192..6335) ----------
__global__ __launch_bounds__(256) void prep_k(const float* __restrict__ x, const float* __restrict__ g1,
                                              const float* __restrict__ be1, unsigned short* __restrict__ h,
                                              const float* __restrict__ Wq, const float* __restrict__ Wk,
                                              const float* __restrict__ Wv, const float* __restrict__ Wo,
                                              const float* __restrict__ W1, const float* __restrict__ W2,
                                              unsigned short* __restrict__ wpackT, unsigned short* __restrict__ woT,
                                              unsigned short* __restrict__ w1T, unsigned short* __restrict__ w2T) {
    __shared__ float t[64][65];
    if (blockIdx.x >= 192) {
        int row  = (blockIdx.x - 192) * 4 + (threadIdx.x >> 6);
        int lane = threadIdx.x & 63;
        f32x4 v = *(const f32x4*)(x + (size_t)row * 256 + lane * 4);
        f32x4 gv = *(const f32x4*)(g1 + lane * 4);
        f32x4 bv = *(const f32x4*)(be1 + lane * 4);
        uint2v u = ln_row_pk(v, gv, bv);
        *(uint2v*)(h + (size_t)row * 256 + lane * 4) = u;
        return;
    }
    const int bid = blockIdx.x;
    const float* in; unsigned short* out;
    int R, C, r0, c0;
    if (bid < 48) {
        int z = bid >> 2, cx = bid & 3;
        int qkv = z >> 2, hh = z & 3;
        in = ((qkv == 0) ? Wq : (qkv == 1) ? Wk : Wv) + (size_t)hh * 256 * 64;
        out = wpackT + (size_t)(qkv * 256 + hh * 64) * 256;
        R = 256; C = 64; r0 = cx * 64; c0 = 0;
    } else if (bid < 64) {
        int tt = bid - 48;
        in = Wo; out = woT; R = 256; C = 256; r0 = (tt >> 2) * 64; c0 = (tt & 3) * 64;
    } else if (bid < 128) {
        int tt = bid - 64;
        in = W1; out = w1T; R = 256; C = 1024; r0 = (tt & 3) * 64; c0 = (tt >> 2) * 64;
    } else {
        int tt = bid - 128;
        in = W2; out = w2T; R = 1024; C = 256; r0 = (tt & 15) * 64; c0 = (tt >> 4) * 64;
    }
    const int tx = threadIdx.x & 63, ty = threadIdx.x >> 6;
    #pragma unroll
    for (int i = 0; i < 64; i += 4)
        t[i + ty][tx] = in[(size_t)(r0 + i + ty) * C + c0 + tx];
    __syncthreads();
    #pragma unroll
    for (int i = 0; i < 64; i += 4)
        out[(size_t)(c0 + i + ty) * R + r0 + tx] = f2bf(t[tx][i + ty]);
}

// ---------- merged QK + V^T GEMM (1152 blocks), XCD-grouped, counted-vmcnt dbuf ----------
__global__ __launch_bounds__(256) void qkv_k(const unsigned short* __restrict__ h,
                                             const unsigned short* __restrict__ wpackT,
                                             unsigned short* __restrict__ qk,
                                             unsigned short* __restrict__ vT) {
    __shared__ unsigned short As[2][128 * 64];   // 32KB
    __shared__ unsigned short Bs[2][128 * 64];   // 32KB
    const int tid  = threadIdx.x;
    const int lane = tid & 63;
    const int w    = tid >> 6;
    const int wm   = w >> 1, wn = w & 1;
    const int l15  = lane & 15, l4 = lane >> 4;
    const int bid  = blockIdx.x;

    const unsigned short *A, *BT;
    unsigned short* outp;
    int bm, bn, N;
    float qsc = 1.0f;
    if (bid < 768) {
        const int xcd = bid & 7, i = bid >> 3;
        bm = xcd * 24 + (i >> 2);
        bn = i & 3;
        A = h; BT = wpackT; outp = qk; N = 512;
        if (bn < 2) qsc = CSC;
    } else {
        const int t = bid - 768;
        const int xcd = t & 7, j = t >> 3;
        bn = xcd * 24 + (j >> 1);
        bm = j & 1;
        A = wpackT + 512 * 256; BT = h; outp = vT; N = 24576;
    }
    const int K = 256;

    f32x4 acc[4][4] = {};

    const size_t K2 = (size_t)K * 2;
    const int i0   = w * 4096 + lane * 16;
    const int row0 = i0 >> 7;
    const int cb0  = (i0 & 127) ^ ((row0 & 7) << 4);
    const char* aSrc = (const char*)A  + ((size_t)(bm * 128 + row0)) * K2 + cb0;
    const char* bSrc = (const char*)BT + ((size_t)(bn * 128 + row0)) * K2 + cb0;

    auto stage = [&](int t, int buf) {
        #pragma unroll
        for (int c = 0; c < 4; ++c) {
            gload16(aSrc + (size_t)t * 128 + (size_t)c * 8 * K2,
                    (char*)&As[buf][0] + w * 4096 + c * 1024);
            gload16(bSrc + (size_t)t * 128 + (size_t)c * 8 * K2,
                    (char*)&Bs[buf][0] + w * 4096 + c * 1024);
        }
    };

    stage(0, 0);
    stage(1, 1);                    // 16 loads/thread in flight

    #pragma unroll
    for (int t = 0; t < 4; ++t) {
        WAITLG();
        if (t < 3) { WAITVM(8); } else { WAITVM(0); }   // tile t done; t+1 stays in flight
        BAR();
        const char* AsB = (const char*)&As[t & 1][0];
        const char* BsB = (const char*)&Bs[t & 1][0];
        #pragma unroll
        for (int kf = 0; kf < 2; ++kf) {
            int kb = kf * 64 + l4 * 16;
            short8 af[4], bfr[4];
            #pragma unroll
            for (int mf = 0; mf < 4; ++mf) {
                int row = wm * 64 + mf * 16 + l15;
                af[mf] = *(const short8*)(AsB + ((row * 128 + kb) ^ ((row & 7) << 4)));
            }
            #pragma unroll
            for (int nf = 0; nf < 4; ++nf) {
                int row = wn * 64 + nf * 16 + l15;
                bfr[nf] = *(const short8*)(BsB + ((row * 128 + kb) ^ ((row & 7) << 4)));
            }
            #pragma unroll
            for (int mf = 0; mf < 4; ++mf)
                #pragma unroll
                for (int nf = 0; nf < 4; ++nf)
                    acc[mf][nf] = __builtin_amdgcn_mfma_f32_16x16x32_bf16(af[mf], bfr[nf], acc[mf][nf], 0, 0, 0);
        }
        BAR();                      // all waves done reading buf t&1
        if (t + 2 < 4) stage(t + 2, t & 1);
    }

    #pragma unroll
    for (int nf = 0; nf < 4; ++nf) {
        int col = bn * 128 + wn * 64 + nf * 16 + l15;
        #pragma unroll
        for (int mf = 0; mf < 4; ++mf) {
            int row0o = bm * 128 + wm * 64 + mf * 16 + l4 * 4;
            size_t off = (size_t)row0o * N + col;
            unsigned p01 = pk2bf(acc[mf][nf][0] * qsc, acc[mf][nf][1] * qsc);
            unsigned p23 = pk2bf(acc[mf][nf][2] * qsc, acc[mf][nf][3] * qsc);
            outp[off]                 = (unsigned short)p01;
            outp[off + (size_t)N]     = (unsigned short)(p01 >> 16);
            outp[off + (size_t)N * 2] = (unsigned short)p23;
            outp[off + (size_t)N * 3] = (unsigned short)(p23 >> 16);
        }
    }
}

// ---------- O-proj GEMM (counted-vmcnt dbuf): x1 = o@Wo + bo + resid(f32) -> bf16 ----------
__global__ __launch_bounds__(256) void oproj_k(const unsigned short* __restrict__ A,
                                               const unsigned short* __restrict__ BT,
                                               unsigned short* __restrict__ outp,
                                               const float* __restrict__ bias,
                                               const float* __restrict__ resid) {
    __shared__ unsigned short As[2][128 * 64];
    __shared__ unsigned short Bs[2][128 * 64];
    const int tid  = threadIdx.x;
    const int lane = tid & 63;
    const int w    = tid >> 6;
    const int wm   = w >> 1, wn = w & 1;
    const int bm   = blockIdx.y, bn = blockIdx.x;
    const int l15  = lane & 15, l4 = lane >> 4;
    const int N = 256;

    f32x4 acc[4][4] = {};

    const size_t K2 = 512;
    const int i0   = w * 4096 + lane * 16;
    const int row0 = i0 >> 7;
    const int cb0  = (i0 & 127) ^ ((row0 & 7) << 4);
    const char* aSrc = (const char*)A  + ((size_t)(bm * 128 + row0)) * K2 + cb0;
    const char* bSrc = (const char*)BT + ((size_t)(bn * 128 + row0)) * K2 + cb0;

    auto stage = [&](int t, int buf) {
        #pragma unroll
        for (int c = 0; c < 4; ++c) {
            gload16(aSrc + (size_t)t * 128 + (size_t)c * 8 * K2,
                    (char*)&As[buf][0] + w * 4096 + c * 1024);
            gload16(bSrc + (size_t)t * 128 + (size_t)c * 8 * K2,
                    (char*)&Bs[buf][0] + w * 4096 + c * 1024);
        }
    };

    stage(0, 0);
    stage(1, 1);

    #pragma unroll
    for (int t = 0; t < 4; ++t) {
        WAITLG();
        if (t < 3) { WAITVM(8); } else { WAITVM(0); }
        BAR();
        const char* AsB = (const char*)&As[t & 1][0];
        const char* BsB = (const char*)&Bs[t & 1][0];
        #pragma unroll
        for (int kf = 0; kf < 2; ++kf) {
            int kb = kf * 64 + l4 * 16;
            short8 af[4], bfr[4];
            #pragma unroll
            for (int mf = 0; mf < 4; ++mf) {
                int row = wm * 64 + mf * 16 + l15;
                af[mf] = *(const short8*)(AsB + ((row * 128 + kb) ^ ((row & 7) << 4)));
            }
            #pragma unroll
            for (int nf = 0; nf < 4; ++nf) {
                int row = wn * 64 + nf * 16 + l15;
                bfr[nf] = *(const short8*)(BsB + ((row * 128 + kb) ^ ((row & 7) << 4)));
            }
            #pragma unroll
            for (int mf = 0; mf < 4; ++mf)
                #pragma unroll
                for (int nf = 0; nf < 4; ++nf)
                    acc[mf][nf] = __builtin_amdgcn_mfma_f32_16x16x32_bf16(af[mf], bfr[nf], acc[mf][nf], 0, 0, 0);
        }
        BAR();
        if (t + 2 < 4) stage(t + 2, t & 1);
    }

    #pragma unroll
    for (int nf = 0; nf < 4; ++nf) {
        int col = bn * 128 + wn * 64 + nf * 16 + l15;
        float bv = bias[col];
        #pragma unroll
        for (int mf = 0; mf < 4; ++mf) {
            int row0o = bm * 128 + wm * 64 + mf * 16 + l4 * 4;
            size_t off = (size_t)row0o * N + col;
            float v[4];
            #pragma unroll
            for (int r = 0; r < 4; ++r)
                v[r] = acc[mf][nf][r] + bv + resid[off + (size_t)r * N];
            unsigned p01 = pk2bf(v[0], v[1]), p23 = pk2bf(v[2], v[3]);
            outp[off]                 = (unsigned short)p01;
            outp[off + (size_t)N]     = (unsigned short)(p01 >> 16);
            outp[off + (size_t)N * 2] = (unsigned short)p23;
            outp[off + (size_t)N * 3] = (unsigned short)(p23 >> 16);
        }
    }
}

// ---------- fused LN2 + FF v8 (R18-proven, FROZEN): counted-vmcnt pipeline ----------
__global__ __launch_bounds__(256) void ff_fused(const unsigned short* __restrict__ x1b,
                                                const float* __restrict__ g2,
                                                const float* __restrict__ be2,
                                                const unsigned short* __restrict__ w1T,
                                                const unsigned short* __restrict__ w2T,
                                                const float* __restrict__ b1,
                                                const float* __restrict__ b2,
                                                float* __restrict__ out) {
    __shared__ __align__(16) char smem[147456];
    const int tid = threadIdx.x, lane = tid & 63, w = tid >> 6;
    const int l15 = lane & 15, l4 = lane >> 4;
    const int wm = w >> 1, wn = w & 1;
    const int r0 = blockIdx.x * 96;

    {
        f32x4 gv = *(const f32x4*)(g2 + lane * 4);
        f32x4 bv = *(const f32x4*)(be2 + lane * 4);
        const int ks = lane >> 4, colb = (lane & 15) * 8;
        #pragma unroll
        for (int it = 0; it < 24; ++it) {
            int row = it * 4 + w;
            ushort4v u4 = *(const ushort4v*)(x1b + (size_t)(r0 + row) * 256 + lane * 4);
            f32x4 v;
            #pragma unroll
            for (int q = 0; q < 4; ++q) v[q] = bf2f(u4[q]);
            uint2v u = ln_row_pk(v, gv, bv);
            *(uint2v*)(smem + ks * 12288 + row * 128 + (colb ^ ((row & 7) << 4))) = u;
        }
    }
    WAITLG(); BAR();

    short8 hfr[3][4][2];
    #pragma unroll
    for (int mf = 0; mf < 3; ++mf) {
        const int row = wm * 48 + mf * 16 + l15;
        #pragma unroll
        for (int ks = 0; ks < 4; ++ks)
            #pragma unroll
            for (int kf = 0; kf < 2; ++kf) {
                const int kb = kf * 64 + l4 * 16;
                hfr[mf][ks][kf] = *(const short8*)(smem + ks * 12288
                                    + ((row * 128 + kb) ^ ((row & 7) << 4)));
            }
    }
    WAITLG(); BAR();

    auto stage_w1 = [&](int c, int buf) {
        const char* wb = (const char*)w1T + (size_t)(c * 64) * 512;
        #pragma unroll
        for (int g = 0; g < 8; ++g) {
            int j = g * 4096 + tid * 16;
            int ks = j >> 13, row = (j >> 7) & 63, cb = j & 127;
            gload16(wb + (size_t)row * 512 + ks * 128 + (cb ^ ((row & 7) << 4)),
                    smem + buf * 32768 + j);
        }
    };
    auto stage_w2 = [&](int c, int buf) {
        const char* wb = (const char*)w2T + (size_t)c * 128;
        #pragma unroll
        for (int g = 0; g < 8; ++g) {
            int j = g * 4096 + tid * 16;
            int row = j >> 7, cb = j & 127;
            gload16(wb + (size_t)row * 2048 + (cb ^ ((row & 7) << 4)),
                    smem + 65536 + buf * 32768 + j);
        }
    };

    gload16((const char*)b1 + tid * 16, smem + 143360 + tid * 16);
    stage_w1(0, 0);
    stage_w2(0, 0);
    stage_w1(1, 1);

    const float* sB1f = (const float*)(smem + 143360);
    f32x4 oacc[3][8] = {};

    for (int c = 0; c < 16; ++c) {
        WAITLG();
        if (c < 15) { WAITVM(16); } else { WAITVM(8); }
        BAR();
        if (c + 1 < 16) stage_w2(c + 1, (c + 1) & 1);

        const char* W1B = smem + (c & 1) * 32768;
        f32x4 aacc[3][2] = {};
        __builtin_amdgcn_s_setprio(1);
        #pragma unroll
        for (int ks = 0; ks < 4; ++ks) {
            #pragma unroll
            for (int kf = 0; kf < 2; ++kf) {
                const int kb = kf * 64 + l4 * 16;
                short8 wf[2];
                #pragma unroll
                for (int nf = 0; nf < 2; ++nf) {
                    int row = wn * 32 + nf * 16 + l15;
                    wf[nf] = *(const short8*)(W1B + ks * 8192
                               + ((row * 128 + kb) ^ ((row & 7) << 4)));
                }
                #pragma unroll
                for (int mf = 0; mf < 3; ++mf)
                    #pragma unroll
                    for (int nf = 0; nf < 2; ++nf)
                        aacc[mf][nf] = __builtin_amdgcn_mfma_f32_16x16x32_bf16(wf[nf], hfr[mf][ks][kf], aacc[mf][nf], 0, 0, 0);
            }
        }
        __builtin_amdgcn_s_setprio(0);
        #pragma unroll
        for (int mf = 0; mf < 3; ++mf)
            #pragma unroll
            for (int nf = 0; nf < 2; ++nf) {
                int nl = wn * 32 + nf * 16 + l4 * 4;
                f32x4 bv = *(const f32x4*)(sB1f + c * 64 + nl);
                float v0 = aacc[mf][nf][0] + bv[0]; v0 = v0 > 0.0f ? v0 : 0.0f;
                float v1 = aacc[mf][nf][1] + bv[1]; v1 = v1 > 0.0f ? v1 : 0.0f;
                float v2 = aacc[mf][nf][2] + bv[2]; v2 = v2 > 0.0f ? v2 : 0.0f;
                float v3 = aacc[mf][nf][3] + bv[3]; v3 = v3 > 0.0f ? v3 : 0.0f;
                uint2v u; u[0] = pk2bf(v0, v1); u[1] = pk2bf(v2, v3);
                int m = wm * 48 + mf * 16 + l15;
                *(uint2v*)(smem + 131072 + ((m * 128 + nl * 2) ^ ((m & 7) << 4))) = u;
            }

        WAITLG();
        if (c < 15) { WAITVM(16); } else { WAITVM(0); }
        BAR();
        if (c + 2 < 16) stage_w1(c + 2, c & 1);

        const char* W2B = smem + 65536 + (c & 1) * 32768;
        __builtin_amdgcn_s_setprio(1);
        #pragma unroll
        for (int kf = 0; kf < 2; ++kf) {
            const int kb = kf * 64 + l4 * 16;
            short8 af[3], wf[8];
            #pragma unroll
            for (int mf = 0; mf < 3; ++mf) {
                int m = wm * 48 + mf * 16 + l15;
                af[mf] = *(const short8*)(smem + 131072 + ((m * 128 + kb) ^ ((m & 7) << 4)));
            }
            #pragma unroll
            for (int nf = 0; nf < 8; ++nf) {
                int n2 = wn * 128 + nf * 16 + l15;
                wf[nf] = *(const short8*)(W2B + ((n2 * 128 + kb) ^ ((n2 & 7) << 4)));
            }
            #pragma unroll
            for (int mf = 0; mf < 3; ++mf)
                #pragma unroll
                for (int nf = 0; nf < 8; ++nf)
                    oacc[mf][nf] = __builtin_amdgcn_mfma_f32_16x16x32_bf16(af[mf], wf[nf], oacc[mf][nf], 0, 0, 0);
        }
        __builtin_amdgcn_s_setprio(0);
    }

    #pragma unroll
    for (int nf = 0; nf < 8; ++nf) {
        const int col = wn * 128 + nf * 16 + l15;
        const float bv = b2[col];
        #pragma unroll
        for (int mf = 0; mf < 3; ++mf) {
            const int row = r0 + wm * 48 + mf * 16 + l4 * 4;
            const size_t off = (size_t)row * 256 + col;
            #pragma unroll
            for (int r = 0; r < 4; ++r)
                out[off + (size_t)r * 256] = oacc[mf][nf][r] + bv + bf2f(x1b[off + (size_t)r * 256]);
        }
    }
}

// ---------- fused causal attention (R6-proven) ----------
__global__ __launch_bounds__(256) void attn_k(const unsigned short* __restrict__ qk,
                                              const unsigned short* __restrict__ vT,
                                              unsigned short* __restrict__ o) {
    __shared__ unsigned short Ks[2][64 * 64];
    __shared__ unsigned short Vt[2][64 * 64];
    __shared__ unsigned short Pl[4][16 * 64];
    const int tid = threadIdx.x, lane = tid & 63, w = tid >> 6;
    const int l15 = lane & 15, l4 = lane >> 4;
    const int gid = blockIdx.x;
    const int xcd = gid & 7, slot = gid >> 3;
    const int sl6 = slot / 6;
    const int bh  = xcd * 16 + sl6;
    const int x   = slot - sl6 * 6;
    const int qb1 = x, qb2 = 11 - x;
    const int b = bh >> 2, h = bh & 3;
    const unsigned short* Qb = qk + (size_t)b * 768 * 512 + h * 64;
    const char* Kg = (const char*)(Qb + 256);
    const char* Vg = (const char*)(vT + (size_t)(h * 64) * 24576 + (size_t)b * 768);
    const int t01 = qb1 * 64, t02 = qb2 * 64;
    const int tq1 = t01 + w * 16 + l15;
    const int tq2 = t02 + w * 16 + l15;

    short8 q1f0 = *(const short8*)(Qb + (size_t)tq1 * 512 + l4 * 8);
    short8 q1f1 = *(const short8*)(Qb + (size_t)tq1 * 512 + 32 + l4 * 8);
    short8 q2f0 = *(const short8*)(Qb + (size_t)tq2 * 512 + l4 * 8);
    short8 q2f1 = *(const short8*)(Qb + (size_t)tq2 * 512 + 32 + l4 * 8);

    const int srow = w * 16 + (lane >> 3);
    const int scb  = ((lane & 7) * 16) ^ ((srow & 7) << 4);
    const char* kSrc = Kg + (size_t)srow * 1024 + scb;
    const char* vSrc = Vg + (size_t)srow * 49152 + scb;
    char* kDst0 = (char*)&Ks[0][0] + w * 2048;
    char* vDst0 = (char*)&Vt[0][0] + w * 2048;

    f32x4 oA[4] = {}, oB[4] = {};
    float lsA = 0.0f, lsB = 0.0f;
    unsigned short* Pw = &Pl[w][0];
    const char* KsB;
    const char* VtB;
    int sb = 0;

    auto do_tile = [&](short8 qf0, short8 qf1, f32x4 (&oacc)[4], float& lsum, bool diag, int tq) {
        f32x4 sacc[4] = {};
        __builtin_amdgcn_s_setprio(1);
        #pragma unroll
        for (int kf = 0; kf < 2; ++kf) {
            const int kb = kf * 64 + l4 * 16;
            short8 qf = kf ? qf1 : qf0;
            #pragma unroll
            for (int nf = 0; nf < 4; ++nf) {
                int sr = nf * 16 + l15;
                short8 kfr = *(const short8*)(KsB + ((sr * 128 + kb) ^ ((sr & 7) << 4)));
                sacc[nf] = __builtin_amdgcn_mfma_f32_16x16x32_bf16(kfr, qf, sacc[nf], 0, 0, 0);
            }
        }
        __builtin_amdgcn_s_setprio(0);

        if (diag) {
            #pragma unroll
            for (int nf = 0; nf < 4; ++nf)
                #pragma unroll
                for (int r = 0; r < 4; ++r) {
                    int s = sb * 64 + nf * 16 + l4 * 4 + r;
                    if (s > tq) sacc[nf][r] = -1e30f;
                }
        }
        float psum = 0.0f;
        #pragma unroll
        for (int nf = 0; nf < 4; ++nf) {
            float p0 = __builtin_amdgcn_exp2f(sacc[nf][0] - FIXC);
            float p1 = __builtin_amdgcn_exp2f(sacc[nf][1] - FIXC);
            float p2 = __builtin_amdgcn_exp2f(sacc[nf][2] - FIXC);
            float p3 = __builtin_amdgcn_exp2f(sacc[nf][3] - FIXC);
            psum += (p0 + p1) + (p2 + p3);
            uint2v u; u[0] = pk2bf(p0, p1); u[1] = pk2bf(p2, p3);
            *(uint2v*)((char*)Pw + ((l15 * 128 + nf * 32 + l4 * 8) ^ ((l15 & 7) << 4))) = u;
        }
        psum += __shfl_xor(psum, 16, 64);
        psum += __shfl_xor(psum, 32, 64);
        lsum += psum;

        __builtin_amdgcn_s_setprio(1);
        #pragma unroll
        for (int kf = 0; kf < 2; ++kf) {
            const int kb = kf * 64 + l4 * 16;
            short8 pa = *(const short8*)((const char*)Pw + ((l15 * 128 + kb) ^ ((l15 & 7) << 4)));
            #pragma unroll
            for (int nf = 0; nf < 4; ++nf) {
                int dr = nf * 16 + l15;
                short8 vfr = *(const short8*)(VtB + ((dr * 128 + kb) ^ ((dr & 7) << 4)));
                oacc[nf] = __builtin_amdgcn_mfma_f32_16x16x32_bf16(pa, vfr, oacc[nf], 0, 0, 0);
            }
        }
        __builtin_amdgcn_s_setprio(0);
    };

    gload16(kSrc, kDst0);                 gload16(kSrc + 8 * 1024, kDst0 + 1024);
    gload16(vSrc, vDst0);                 gload16(vSrc + 8 * 49152, vDst0 + 1024);

    for (sb = 0; sb <= qb2; ++sb) {
        const int pb = sb & 1;
        __syncthreads();
        if (sb < qb2) {
            const char* ks = kSrc + (size_t)(sb + 1) * 65536;
            const char* vs = vSrc + (size_t)(sb + 1) * 128;
            char* kd = kDst0 + (pb ^ 1) * 8192;
            char* vd = vDst0 + (pb ^ 1) * 8192;
            gload16(ks, kd);              gload16(ks + 8 * 1024, kd + 1024);
            gload16(vs, vd);              gload16(vs + 8 * 49152, vd + 1024);
        }
        KsB = (const char*)&Ks[0][0] + pb * 8192;
        VtB = (const char*)&Vt[0][0] + pb * 8192;

        do_tile(q2f0, q2f1, oB, lsB, sb == qb2, tq2);
        if (sb <= qb1) do_tile(q1f0, q1f1, oA, lsA, sb == qb1, tq1);
    }

    float liA = 1.0f / lsA, liB = 1.0f / lsB;
    float lrA[4], lrB[4];
    #pragma unroll
    for (int r = 0; r < 4; ++r) {
        lrA[r] = __shfl(liA, l4 * 4 + r, 64);
        lrB[r] = __shfl(liB, l4 * 4 + r, 64);
    }
    const int tA = t01 + w * 16 + l4 * 4;
    const int tB = t02 + w * 16 + l4 * 4;
    unsigned short* oa = o + ((size_t)(b * 768 + tA)) * 256 + h * 64;
    unsigned short* ob = o + ((size_t)(b * 768 + tB)) * 256 + h * 64;
    #pragma unroll
    for (int nf = 0; nf < 4; ++nf) {
        unsigned a01 = pk2bf(oA[nf][0] * lrA[0], oA[nf][1] * lrA[1]);
        unsigned a23 = pk2bf(oA[nf][2] * lrA[2], oA[nf][3] * lrA[3]);
        unsigned b01 = pk2bf(oB[nf][0] * lrB[0], oB[nf][1] * lrB[1]);
        unsigned b23 = pk2bf(oB[nf][2] * lrB[2], oB[nf][3] * lrB[3]);
        oa[nf * 16 + l15]       = (unsigned short)a01;
        oa[256 + nf * 16 + l15] = (unsigned short)(a01 >> 16);
        oa[512 + nf * 16 + l15] = (unsigned short)a23;
        oa[768 + nf * 16 + l15] = (unsigned short)(a23 >> 16);
        ob[nf * 16 + l15]       = (unsigned short)b01;
        ob[256 + nf * 16 + l15] = (unsigned short)(b01 >> 16);
        ob[512 + nf * 16 + l15] = (unsigned short)b23;
        ob[768 + nf * 16 + l15] = (unsigned short)(b23 >> 16);
    }
}

// ---------- launch ----------
extern "C" void kernel_launch(void* const* d_in, const int* in_sizes, int n_in,
                              void* d_out, int out_size, void* d_ws, size_t ws_size,
                              hipStream_t stream) {
    const float* x   = (const float*)d_in[0];
    const float* Wq  = (const float*)d_in[1];
    const float* Wk  = (const float*)d_in[2];
    const float* Wv  = (const float*)d_in[3];
    const float* Wo  = (const float*)d_in[4];
    const float* bo  = (const float*)d_in[5];
    const float* W1  = (const float*)d_in[6];
    const float* b1  = (const float*)d_in[7];
    const float* W2  = (const float*)d_in[8];
    const float* b2  = (const float*)d_in[9];
    const float* g1  = (const float*)d_in[10];
    const float* be1 = (const float*)d_in[11];
    const float* g2  = (const float*)d_in[12];
    const float* be2 = (const float*)d_in[13];

    char* ws = (char*)d_ws;
    unsigned short* qk_ws  = (unsigned short*)(ws + 0);          // 24576x512 bf16
    unsigned short* vT_ws  = (unsigned short*)(ws + 25165824);   // 256x24576 bf16
    unsigned short* o_ws   = (unsigned short*)(ws + 37748736);   // 24576x256 bf16
    unsigned short* h_ws   = (unsigned short*)(ws + 50331648);   // 24576x256 bf16 (LN1 out)
    unsigned short* x1b_ws = (unsigned short*)(ws + 62914560);   // 24576x256 bf16 residual
    unsigned short* wpackT = (unsigned short*)(ws + 88080384);   // 768x256 bf16
    unsigned short* woT    = (unsigned short*)(ws + 88473600);   // 256x256
    unsigned short* w1T    = (unsigned short*)(ws + 88604672);   // 1024x256
    unsigned short* w2T    = (unsigned short*)(ws + 89128960);   // 256x1024

    // transposes (192 blocks) + LN1 (6144 blocks)
    prep_k<<<6336, 256, 0, stream>>>(x, g1, be1, h_ws, Wq, Wk, Wv, Wo, W1, W2, wpackT, woT, w1T, w2T);
    // merged: QK [24576x512] (Q pre-scaled) + V^T [256x24576], XCD-grouped, counted-vmcnt dbuf
    qkv_k<<<1152, 256, 0, stream>>>(h_ws, wpackT, qk_ws, vT_ws);
    attn_k<<<768, 256, 0, stream>>>(qk_ws, vT_ws, o_ws);
    // O-proj + bo + resid(x, f32) -> x1 (bf16), counted-vmcnt dbuf
    oproj_k<<<dim3(2, 192), 256, 0, stream>>>(o_ws, woT, x1b_ws, bo, x);
    // fused LN2 + FF v8 (counted-vmcnt pipeline, frozen): out = x1 + ReLU(LN2(x1)@W1+b1)@W2 + b2
    ff_fused<<<256, 256, 0, stream>>>(x1b_ws, g2, be2, w1T, w2T, b1, b2, (float*)d_out);
}

// Round 21
// 101.855 us; speedup vs baseline: 1.1595x; 1.0690x over previous
//
#include <hip/hip_runtime.h>
#include <stdint.h>

// ---------- types ----------
using short8   = __attribute__((ext_vector_type(8))) short;   // 8 x bf16 = 16B
using f32x4    = __attribute__((ext_vector_type(4))) float;
using ushort4v = __attribute__((ext_vector_type(4))) unsigned short;
using uint2v   = __attribute__((ext_vector_type(2))) unsigned int;

#define CSC  0.1803368801111f   // 0.125 * log2(e): QK^T lands in log2 units
#define FIXC 20.0f              // fixed softmax exponent offset (power-of-2: bit-exact)

#define WAITLG()   asm volatile("s_waitcnt lgkmcnt(0)" ::: "memory")
#define WAITVM(n)  asm volatile("s_waitcnt vmcnt(" #n ")" ::: "memory")
#define BAR()      __builtin_amdgcn_s_barrier()

__device__ __forceinline__ unsigned short f2bf(float f) {
    unsigned int u = __builtin_bit_cast(unsigned int, f);
    u += 0x7FFFu + ((u >> 16) & 1u);
    return (unsigned short)(u >> 16);
}
__device__ __forceinline__ float bf2f(unsigned short s) {
    unsigned int u = ((unsigned int)s) << 16;
    return __builtin_bit_cast(float, u);
}
// packed f32x2 -> bf16x2 (RNE), 1 VALU op
__device__ __forceinline__ unsigned pk2bf(float a, float b) {
    unsigned r;
    asm("v_cvt_pk_bf16_f32 %0, %1, %2" : "=v"(r) : "v"(a), "v"(b));
    return r;
}

// async global->LDS, 16B per lane. LDS dest = wave-uniform base + lane*16.
__device__ __forceinline__ void gload16(const void* g, void* l) {
    __builtin_amdgcn_global_load_lds(
        (const __attribute__((address_space(1))) void*)(uintptr_t)g,
        (__attribute__((address_space(3))) void*)(unsigned)(uintptr_t)l,
        16, 0, 0);
}

// ---------- shared LN row body (one wave, 256-wide row), result packed bf16x4 ----------
__device__ __forceinline__ uint2v ln_row_pk(f32x4 v, f32x4 gv, f32x4 bvv) {
    float s  = v[0] + v[1] + v[2] + v[3];
    float s2 = v[0]*v[0] + v[1]*v[1] + v[2]*v[2] + v[3]*v[3];
    for (int m = 1; m < 64; m <<= 1) {
        s  += __shfl_xor(s,  m, 64);
        s2 += __shfl_xor(s2, m, 64);
    }
    float mu  = s * (1.0f / 256.0f);
    float var = s2 * (1.0f / 256.0f) - mu * mu;
    float rs  = rsqrtf(var + 1e-5f);
    float r0 = (v[0] - mu) * rs * gv[0] + bvv[0];
    float r1 = (v[1] - mu) * rs * gv[1] + bvv[1];
    float r2 = (v[2] - mu) * rs * gv[2] + bvv[2];
    float r3 = (v[3] - mu) * rs * gv[3] + bvv[3];
    uint2v u; u[0] = pk2bf(r0, r1); u[1] = pk2bf(r2, r3);
    return u;
}

// ---------- prep: weight transposes (blocks 0..191) + LN1 (blocks 192..6335) ----------
__global__ __launch_bounds__(256) void prep_k(const float* __restrict__ x, const float* __restrict__ g1,
                                              const float* __restrict__ be1, unsigned short* __restrict__ h,
                                              const float* __restrict__ Wq, const float* __restrict__ Wk,
                                              const float* __restrict__ Wv, const float* __restrict__ Wo,
                                              const float* __restrict__ W1, const float* __restrict__ W2,
                                              unsigned short* __restrict__ wpackT, unsigned short* __restrict__ woT,
                                              unsigned short* __restrict__ w1T, unsigned short* __restrict__ w2T) {
    __shared__ float t[64][65];
    if (blockIdx.x >= 192) {
        int row  = (blockIdx.x - 192) * 4 + (threadIdx.x >> 6);
        int lane = threadIdx.x & 63;
        f32x4 v = *(const f32x4*)(x + (size_t)row * 256 + lane * 4);
        f32x4 gv = *(const f32x4*)(g1 + lane * 4);
        f32x4 bv = *(const f32x4*)(be1 + lane * 4);
        uint2v u = ln_row_pk(v, gv, bv);
        *(uint2v*)(h + (size_t)row * 256 + lane * 4) = u;
        return;
    }
    const int bid = blockIdx.x;
    const float* in; unsigned short* out;
    int R, C, r0, c0;
    if (bid < 48) {
        int z = bid >> 2, cx = bid & 3;
        int qkv = z >> 2, hh = z & 3;
        in = ((qkv == 0) ? Wq : (qkv == 1) ? Wk : Wv) + (size_t)hh * 256 * 64;
        out = wpackT + (size_t)(qkv * 256 + hh * 64) * 256;
        R = 256; C = 64; r0 = cx * 64; c0 = 0;
    } else if (bid < 64) {
        int tt = bid - 48;
        in = Wo; out = woT; R = 256; C = 256; r0 = (tt >> 2) * 64; c0 = (tt & 3) * 64;
    } else if (bid < 128) {
        int tt = bid - 64;
        in = W1; out = w1T; R = 256; C = 1024; r0 = (tt & 3) * 64; c0 = (tt >> 2) * 64;
    } else {
        int tt = bid - 128;
        in = W2; out = w2T; R = 1024; C = 256; r0 = (tt & 15) * 64; c0 = (tt >> 4) * 64;
    }
    const int tx = threadIdx.x & 63, ty = threadIdx.x >> 6;
    #pragma unroll
    for (int i = 0; i < 64; i += 4)
        t[i + ty][tx] = in[(size_t)(r0 + i + ty) * C + c0 + tx];
    __syncthreads();
    #pragma unroll
    for (int i = 0; i < 64; i += 4)
        out[(size_t)(c0 + i + ty) * R + r0 + tx] = f2bf(t[tx][i + ty]);
}

// ---------- merged QK + V^T GEMM (1152 blocks), XCD-grouped, counted-vmcnt dbuf (R20-proven) ----------
__global__ __launch_bounds__(256) void qkv_k(const unsigned short* __restrict__ h,
                                             const unsigned short* __restrict__ wpackT,
                                             unsigned short* __restrict__ qk,
                                             unsigned short* __restrict__ vT) {
    __shared__ unsigned short As[2][128 * 64];
    __shared__ unsigned short Bs[2][128 * 64];
    const int tid  = threadIdx.x;
    const int lane = tid & 63;
    const int w    = tid >> 6;
    const int wm   = w >> 1, wn = w & 1;
    const int l15  = lane & 15, l4 = lane >> 4;
    const int bid  = blockIdx.x;

    const unsigned short *A, *BT;
    unsigned short* outp;
    int bm, bn, N;
    float qsc = 1.0f;
    if (bid < 768) {
        const int xcd = bid & 7, i = bid >> 3;
        bm = xcd * 24 + (i >> 2);
        bn = i & 3;
        A = h; BT = wpackT; outp = qk; N = 512;
        if (bn < 2) qsc = CSC;
    } else {
        const int t = bid - 768;
        const int xcd = t & 7, j = t >> 3;
        bn = xcd * 24 + (j >> 1);
        bm = j & 1;
        A = wpackT + 512 * 256; BT = h; outp = vT; N = 24576;
    }
    const int K = 256;

    f32x4 acc[4][4] = {};

    const size_t K2 = (size_t)K * 2;
    const int i0   = w * 4096 + lane * 16;
    const int row0 = i0 >> 7;
    const int cb0  = (i0 & 127) ^ ((row0 & 7) << 4);
    const char* aSrc = (const char*)A  + ((size_t)(bm * 128 + row0)) * K2 + cb0;
    const char* bSrc = (const char*)BT + ((size_t)(bn * 128 + row0)) * K2 + cb0;

    auto stage = [&](int t, int buf) {
        #pragma unroll
        for (int c = 0; c < 4; ++c) {
            gload16(aSrc + (size_t)t * 128 + (size_t)c * 8 * K2,
                    (char*)&As[buf][0] + w * 4096 + c * 1024);
            gload16(bSrc + (size_t)t * 128 + (size_t)c * 8 * K2,
                    (char*)&Bs[buf][0] + w * 4096 + c * 1024);
        }
    };

    stage(0, 0);
    stage(1, 1);

    #pragma unroll
    for (int t = 0; t < 4; ++t) {
        WAITLG();
        if (t < 3) { WAITVM(8); } else { WAITVM(0); }
        BAR();
        const char* AsB = (const char*)&As[t & 1][0];
        const char* BsB = (const char*)&Bs[t & 1][0];
        #pragma unroll
        for (int kf = 0; kf < 2; ++kf) {
            int kb = kf * 64 + l4 * 16;
            short8 af[4], bfr[4];
            #pragma unroll
            for (int mf = 0; mf < 4; ++mf) {
                int row = wm * 64 + mf * 16 + l15;
                af[mf] = *(const short8*)(AsB + ((row * 128 + kb) ^ ((row & 7) << 4)));
            }
            #pragma unroll
            for (int nf = 0; nf < 4; ++nf) {
                int row = wn * 64 + nf * 16 + l15;
                bfr[nf] = *(const short8*)(BsB + ((row * 128 + kb) ^ ((row & 7) << 4)));
            }
            #pragma unroll
            for (int mf = 0; mf < 4; ++mf)
                #pragma unroll
                for (int nf = 0; nf < 4; ++nf)
                    acc[mf][nf] = __builtin_amdgcn_mfma_f32_16x16x32_bf16(af[mf], bfr[nf], acc[mf][nf], 0, 0, 0);
        }
        BAR();
        if (t + 2 < 4) stage(t + 2, t & 1);
    }

    #pragma unroll
    for (int nf = 0; nf < 4; ++nf) {
        int col = bn * 128 + wn * 64 + nf * 16 + l15;
        #pragma unroll
        for (int mf = 0; mf < 4; ++mf) {
            int row0o = bm * 128 + wm * 64 + mf * 16 + l4 * 4;
            size_t off = (size_t)row0o * N + col;
            unsigned p01 = pk2bf(acc[mf][nf][0] * qsc, acc[mf][nf][1] * qsc);
            unsigned p23 = pk2bf(acc[mf][nf][2] * qsc, acc[mf][nf][3] * qsc);
            outp[off]                 = (unsigned short)p01;
            outp[off + (size_t)N]     = (unsigned short)(p01 >> 16);
            outp[off + (size_t)N * 2] = (unsigned short)p23;
            outp[off + (size_t)N * 3] = (unsigned short)(p23 >> 16);
        }
    }
}

// ---------- O-proj GEMM (counted-vmcnt dbuf, R20-proven) ----------
__global__ __launch_bounds__(256) void oproj_k(const unsigned short* __restrict__ A,
                                               const unsigned short* __restrict__ BT,
                                               unsigned short* __restrict__ outp,
                                               const float* __restrict__ bias,
                                               const float* __restrict__ resid) {
    __shared__ unsigned short As[2][128 * 64];
    __shared__ unsigned short Bs[2][128 * 64];
    const int tid  = threadIdx.x;
    const int lane = tid & 63;
    const int w    = tid >> 6;
    const int wm   = w >> 1, wn = w & 1;
    const int bm   = blockIdx.y, bn = blockIdx.x;
    const int l15  = lane & 15, l4 = lane >> 4;
    const int N = 256;

    f32x4 acc[4][4] = {};

    const size_t K2 = 512;
    const int i0   = w * 4096 + lane * 16;
    const int row0 = i0 >> 7;
    const int cb0  = (i0 & 127) ^ ((row0 & 7) << 4);
    const char* aSrc = (const char*)A  + ((size_t)(bm * 128 + row0)) * K2 + cb0;
    const char* bSrc = (const char*)BT + ((size_t)(bn * 128 + row0)) * K2 + cb0;

    auto stage = [&](int t, int buf) {
        #pragma unroll
        for (int c = 0; c < 4; ++c) {
            gload16(aSrc + (size_t)t * 128 + (size_t)c * 8 * K2,
                    (char*)&As[buf][0] + w * 4096 + c * 1024);
            gload16(bSrc + (size_t)t * 128 + (size_t)c * 8 * K2,
                    (char*)&Bs[buf][0] + w * 4096 + c * 1024);
        }
    };

    stage(0, 0);
    stage(1, 1);

    #pragma unroll
    for (int t = 0; t < 4; ++t) {
        WAITLG();
        if (t < 3) { WAITVM(8); } else { WAITVM(0); }
        BAR();
        const char* AsB = (const char*)&As[t & 1][0];
        const char* BsB = (const char*)&Bs[t & 1][0];
        #pragma unroll
        for (int kf = 0; kf < 2; ++kf) {
            int kb = kf * 64 + l4 * 16;
            short8 af[4], bfr[4];
            #pragma unroll
            for (int mf = 0; mf < 4; ++mf) {
                int row = wm * 64 + mf * 16 + l15;
                af[mf] = *(const short8*)(AsB + ((row * 128 + kb) ^ ((row & 7) << 4)));
            }
            #pragma unroll
            for (int nf = 0; nf < 4; ++nf) {
                int row = wn * 64 + nf * 16 + l15;
                bfr[nf] = *(const short8*)(BsB + ((row * 128 + kb) ^ ((row & 7) << 4)));
            }
            #pragma unroll
            for (int mf = 0; mf < 4; ++mf)
                #pragma unroll
                for (int nf = 0; nf < 4; ++nf)
                    acc[mf][nf] = __builtin_amdgcn_mfma_f32_16x16x32_bf16(af[mf], bfr[nf], acc[mf][nf], 0, 0, 0);
        }
        BAR();
        if (t + 2 < 4) stage(t + 2, t & 1);
    }

    #pragma unroll
    for (int nf = 0; nf < 4; ++nf) {
        int col = bn * 128 + wn * 64 + nf * 16 + l15;
        float bv = bias[col];
        #pragma unroll
        for (int mf = 0; mf < 4; ++mf) {
            int row0o = bm * 128 + wm * 64 + mf * 16 + l4 * 4;
            size_t off = (size_t)row0o * N + col;
            float v[4];
            #pragma unroll
            for (int r = 0; r < 4; ++r)
                v[r] = acc[mf][nf][r] + bv + resid[off + (size_t)r * N];
            unsigned p01 = pk2bf(v[0], v[1]), p23 = pk2bf(v[2], v[3]);
            outp[off]                 = (unsigned short)p01;
            outp[off + (size_t)N]     = (unsigned short)(p01 >> 16);
            outp[off + (size_t)N * 2] = (unsigned short)p23;
            outp[off + (size_t)N * 3] = (unsigned short)(p23 >> 16);
        }
    }
}

// ---------- fused LN2 + FF v9: v8 schedule at 512 threads (8 waves -> 2 waves/SIMD) ----------
// Same M=96/grid=256/traffic/layouts; N-dim split 4-ways across wn. Intra-SIMD TLP
// is the one axis never varied at fixed traffic; all dep-latency chains halve.
// smem: [0,64K) W1 dbuf | [64K,128K) W2 dbuf | [128K,140K) sAct | [140K,148K) b1 dup.
__global__ __launch_bounds__(512, 2) void ff_fused(const unsigned short* __restrict__ x1b,
                                                   const float* __restrict__ g2,
                                                   const float* __restrict__ be2,
                                                   const unsigned short* __restrict__ w1T,
                                                   const unsigned short* __restrict__ w2T,
                                                   const float* __restrict__ b1,
                                                   const float* __restrict__ b2,
                                                   float* __restrict__ out) {
    __shared__ __align__(16) char smem[151552];
    const int tid = threadIdx.x, lane = tid & 63, w = tid >> 6;   // w in [0,8)
    const int l15 = lane & 15, l4 = lane >> 4;
    const int wm = w >> 2, wn = w & 3;
    const int r0 = blockIdx.x * 96;

    // ---- LN2 prologue: 96 rows (8 waves x 12 iters) -> sA overlaying smem[0,48K) ----
    {
        f32x4 gv = *(const f32x4*)(g2 + lane * 4);
        f32x4 bv = *(const f32x4*)(be2 + lane * 4);
        const int ks = lane >> 4, colb = (lane & 15) * 8;
        #pragma unroll
        for (int it = 0; it < 12; ++it) {
            int row = it * 8 + w;
            ushort4v u4 = *(const ushort4v*)(x1b + (size_t)(r0 + row) * 256 + lane * 4);
            f32x4 v;
            #pragma unroll
            for (int q = 0; q < 4; ++q) v[q] = bf2f(u4[q]);
            uint2v u = ln_row_pk(v, gv, bv);
            *(uint2v*)(smem + ks * 12288 + row * 128 + (colb ^ ((row & 7) << 4))) = u;
        }
    }
    WAITLG(); BAR();                 // LN2 writes visible

    // ---- hoist A-fragments to registers (per wm; shared across wn waves) ----
    short8 hfr[3][4][2];             // [mf][ks][kf]
    #pragma unroll
    for (int mf = 0; mf < 3; ++mf) {
        const int row = wm * 48 + mf * 16 + l15;
        #pragma unroll
        for (int ks = 0; ks < 4; ++ks)
            #pragma unroll
            for (int kf = 0; kf < 2; ++kf) {
                const int kb = kf * 64 + l4 * 16;
                hfr[mf][ks][kf] = *(const short8*)(smem + ks * 12288
                                    + ((row * 128 + kb) ^ ((row & 7) << 4)));
            }
    }
    WAITLG(); BAR();                 // hoist reads done -> sA space reusable

    auto stage_w1 = [&](int c, int buf) {       // 4 loads/thread
        const char* wb = (const char*)w1T + (size_t)(c * 64) * 512;
        #pragma unroll
        for (int g = 0; g < 4; ++g) {
            int j = g * 8192 + tid * 16;
            int ks = j >> 13, row = (j >> 7) & 63, cb = j & 127;
            gload16(wb + (size_t)row * 512 + ks * 128 + (cb ^ ((row & 7) << 4)),
                    smem + buf * 32768 + j);
        }
    };
    auto stage_w2 = [&](int c, int buf) {       // 4 loads/thread
        const char* wb = (const char*)w2T + (size_t)c * 128;
        #pragma unroll
        for (int g = 0; g < 4; ++g) {
            int j = g * 8192 + tid * 16;
            int row = j >> 7, cb = j & 127;
            gload16(wb + (size_t)row * 2048 + (cb ^ ((row & 7) << 4)),
                    smem + 65536 + buf * 32768 + j);
        }
    };

    // prologue: b1 (duplicated, 1 load/thread, wave-uniform counts) + w1(0) + w2(0) + w1(1)
    gload16((const char*)b1 + (tid & 255) * 16, smem + 143360 + tid * 16);
    stage_w1(0, 0);
    stage_w2(0, 0);
    stage_w1(1, 1);                  // 13 outstanding/thread

    const float* sB1f = (const float*)(smem + 143360);
    f32x4 oacc[3][4] = {};           // wave = 48 rows (wm) x 64 cols (wn)

    for (int c = 0; c < 16; ++c) {
        // ---- w1[c] (and b1 on c==0) ready; w2[c]+w1[c+1] stay in flight ----
        WAITLG();
        if (c < 15) { WAITVM(8); } else { WAITVM(4); }
        BAR();
        if (c + 1 < 16) stage_w2(c + 1, (c + 1) & 1);

        // act GEMM: A from registers, B from W1b[c&1]; wave n1-slice = wn*16
        const char* W1B = smem + (c & 1) * 32768;
        f32x4 aacc[3] = {};
        __builtin_amdgcn_s_setprio(1);
        #pragma unroll
        for (int ks = 0; ks < 4; ++ks) {
            #pragma unroll
            for (int kf = 0; kf < 2; ++kf) {
                const int kb = kf * 64 + l4 * 16;
                int row = wn * 16 + l15;
                short8 wf = *(const short8*)(W1B + ks * 8192
                              + ((row * 128 + kb) ^ ((row & 7) << 4)));
                #pragma unroll
                for (int mf = 0; mf < 3; ++mf)
                    aacc[mf] = __builtin_amdgcn_mfma_f32_16x16x32_bf16(wf, hfr[mf][ks][kf], aacc[mf], 0, 0, 0);
            }
        }
        __builtin_amdgcn_s_setprio(0);
        // +b1 (LDS), ReLU, pack -> sAct
        #pragma unroll
        for (int mf = 0; mf < 3; ++mf) {
            int nl = wn * 16 + l4 * 4;
            f32x4 bv = *(const f32x4*)(sB1f + c * 64 + nl);
            float v0 = aacc[mf][0] + bv[0]; v0 = v0 > 0.0f ? v0 : 0.0f;
            float v1 = aacc[mf][1] + bv[1]; v1 = v1 > 0.0f ? v1 : 0.0f;
            float v2 = aacc[mf][2] + bv[2]; v2 = v2 > 0.0f ? v2 : 0.0f;
            float v3 = aacc[mf][3] + bv[3]; v3 = v3 > 0.0f ? v3 : 0.0f;
            uint2v u; u[0] = pk2bf(v0, v1); u[1] = pk2bf(v2, v3);
            int m = wm * 48 + mf * 16 + l15;
            *(uint2v*)(smem + 131072 + ((m * 128 + nl * 2) ^ ((m & 7) << 4))) = u;
        }

        // ---- w2[c] ready; sAct published; w1[c+1]+w2[c+1] stay in flight ----
        WAITLG();
        if (c < 15) { WAITVM(8); } else { WAITVM(0); }
        BAR();
        if (c + 2 < 16) stage_w1(c + 2, c & 1);

        // FF2 partial: wave n2-slice = wn*64 .. +64
        const char* W2B = smem + 65536 + (c & 1) * 32768;
        __builtin_amdgcn_s_setprio(1);
        #pragma unroll
        for (int kf = 0; kf < 2; ++kf) {
            const int kb = kf * 64 + l4 * 16;
            short8 af[3], wf[4];
            #pragma unroll
            for (int mf = 0; mf < 3; ++mf) {
                int m = wm * 48 + mf * 16 + l15;
                af[mf] = *(const short8*)(smem + 131072 + ((m * 128 + kb) ^ ((m & 7) << 4)));
            }
            #pragma unroll
            for (int nf = 0; nf < 4; ++nf) {
                int n2 = wn * 64 + nf * 16 + l15;
                wf[nf] = *(const short8*)(W2B + ((n2 * 128 + kb) ^ ((n2 & 7) << 4)));
            }
            #pragma unroll
            for (int mf = 0; mf < 3; ++mf)
                #pragma unroll
                for (int nf = 0; nf < 4; ++nf)
                    oacc[mf][nf] = __builtin_amdgcn_mfma_f32_16x16x32_bf16(af[mf], wf[nf], oacc[mf][nf], 0, 0, 0);
        }
        __builtin_amdgcn_s_setprio(0);
    }

    // epilogue: + b2 + resid(bf16) -> f32 out
    #pragma unroll
    for (int nf = 0; nf < 4; ++nf) {
        const int col = wn * 64 + nf * 16 + l15;
        const float bv = b2[col];
        #pragma unroll
        for (int mf = 0; mf < 3; ++mf) {
            const int row = r0 + wm * 48 + mf * 16 + l4 * 4;
            const size_t off = (size_t)row * 256 + col;
            #pragma unroll
            for (int r = 0; r < 4; ++r)
                out[off + (size_t)r * 256] = oacc[mf][nf][r] + bv + bf2f(x1b[off + (size_t)r * 256]);
        }
    }
}

// ---------- fused causal attention (R6-proven) ----------
__global__ __launch_bounds__(256) void attn_k(const unsigned short* __restrict__ qk,
                                              const unsigned short* __restrict__ vT,
                                              unsigned short* __restrict__ o) {
    __shared__ unsigned short Ks[2][64 * 64];
    __shared__ unsigned short Vt[2][64 * 64];
    __shared__ unsigned short Pl[4][16 * 64];
    const int tid = threadIdx.x, lane = tid & 63, w = tid >> 6;
    const int l15 = lane & 15, l4 = lane >> 4;
    const int gid = blockIdx.x;
    const int xcd = gid & 7, slot = gid >> 3;
    const int sl6 = slot / 6;
    const int bh  = xcd * 16 + sl6;
    const int x   = slot - sl6 * 6;
    const int qb1 = x, qb2 = 11 - x;
    const int b = bh >> 2, h = bh & 3;
    const unsigned short* Qb = qk + (size_t)b * 768 * 512 + h * 64;
    const char* Kg = (const char*)(Qb + 256);
    const char* Vg = (const char*)(vT + (size_t)(h * 64) * 24576 + (size_t)b * 768);
    const int t01 = qb1 * 64, t02 = qb2 * 64;
    const int tq1 = t01 + w * 16 + l15;
    const int tq2 = t02 + w * 16 + l15;

    short8 q1f0 = *(const short8*)(Qb + (size_t)tq1 * 512 + l4 * 8);
    short8 q1f1 = *(const short8*)(Qb + (size_t)tq1 * 512 + 32 + l4 * 8);
    short8 q2f0 = *(const short8*)(Qb + (size_t)tq2 * 512 + l4 * 8);
    short8 q2f1 = *(const short8*)(Qb + (size_t)tq2 * 512 + 32 + l4 * 8);

    const int srow = w * 16 + (lane >> 3);
    const int scb  = ((lane & 7) * 16) ^ ((srow & 7) << 4);
    const char* kSrc = Kg + (size_t)srow * 1024 + scb;
    const char* vSrc = Vg + (size_t)srow * 49152 + scb;
    char* kDst0 = (char*)&Ks[0][0] + w * 2048;
    char* vDst0 = (char*)&Vt[0][0] + w * 2048;

    f32x4 oA[4] = {}, oB[4] = {};
    float lsA = 0.0f, lsB = 0.0f;
    unsigned short* Pw = &Pl[w][0];
    const char* KsB;
    const char* VtB;
    int sb = 0;

    auto do_tile = [&](short8 qf0, short8 qf1, f32x4 (&oacc)[4], float& lsum, bool diag, int tq) {
        f32x4 sacc[4] = {};
        __builtin_amdgcn_s_setprio(1);
        #pragma unroll
        for (int kf = 0; kf < 2; ++kf) {
            const int kb = kf * 64 + l4 * 16;
            short8 qf = kf ? qf1 : qf0;
            #pragma unroll
            for (int nf = 0; nf < 4; ++nf) {
                int sr = nf * 16 + l15;
                short8 kfr = *(const short8*)(KsB + ((sr * 128 + kb) ^ ((sr & 7) << 4)));
                sacc[nf] = __builtin_amdgcn_mfma_f32_16x16x32_bf16(kfr, qf, sacc[nf], 0, 0, 0);
            }
        }
        __builtin_amdgcn_s_setprio(0);

        if (diag) {
            #pragma unroll
            for (int nf = 0; nf < 4; ++nf)
                #pragma unroll
                for (int r = 0; r < 4; ++r) {
                    int s = sb * 64 + nf * 16 + l4 * 4 + r;
                    if (s > tq) sacc[nf][r] = -1e30f;
                }
        }
        float psum = 0.0f;
        #pragma unroll
        for (int nf = 0; nf < 4; ++nf) {
            float p0 = __builtin_amdgcn_exp2f(sacc[nf][0] - FIXC);
            float p1 = __builtin_amdgcn_exp2f(sacc[nf][1] - FIXC);
            float p2 = __builtin_amdgcn_exp2f(sacc[nf][2] - FIXC);
            float p3 = __builtin_amdgcn_exp2f(sacc[nf][3] - FIXC);
            psum += (p0 + p1) + (p2 + p3);
            uint2v u; u[0] = pk2bf(p0, p1); u[1] = pk2bf(p2, p3);
            *(uint2v*)((char*)Pw + ((l15 * 128 + nf * 32 + l4 * 8) ^ ((l15 & 7) << 4))) = u;
        }
        psum += __shfl_xor(psum, 16, 64);
        psum += __shfl_xor(psum, 32, 64);
        lsum += psum;

        __builtin_amdgcn_s_setprio(1);
        #pragma unroll
        for (int kf = 0; kf < 2; ++kf) {
            const int kb = kf * 64 + l4 * 16;
            short8 pa = *(const short8*)((const char*)Pw + ((l15 * 128 + kb) ^ ((l15 & 7) << 4)));
            #pragma unroll
            for (int nf = 0; nf < 4; ++nf) {
                int dr = nf * 16 + l15;
                short8 vfr = *(const short8*)(VtB + ((dr * 128 + kb) ^ ((dr & 7) << 4)));
                oacc[nf] = __builtin_amdgcn_mfma_f32_16x16x32_bf16(pa, vfr, oacc[nf], 0, 0, 0);
            }
        }
        __builtin_amdgcn_s_setprio(0);
    };

    gload16(kSrc, kDst0);                 gload16(kSrc + 8 * 1024, kDst0 + 1024);
    gload16(vSrc, vDst0);                 gload16(vSrc + 8 * 49152, vDst0 + 1024);

    for (sb = 0; sb <= qb2; ++sb) {
        const int pb = sb & 1;
        __syncthreads();
        if (sb < qb2) {
            const char* ks = kSrc + (size_t)(sb + 1) * 65536;
            const char* vs = vSrc + (size_t)(sb + 1) * 128;
            char* kd = kDst0 + (pb ^ 1) * 8192;
            char* vd = vDst0 + (pb ^ 1) * 8192;
            gload16(ks, kd);              gload16(ks + 8 * 1024, kd + 1024);
            gload16(vs, vd);              gload16(vs + 8 * 49152, vd + 1024);
        }
        KsB = (const char*)&Ks[0][0] + pb * 8192;
        VtB = (const char*)&Vt[0][0] + pb * 8192;

        do_tile(q2f0, q2f1, oB, lsB, sb == qb2, tq2);
        if (sb <= qb1) do_tile(q1f0, q1f1, oA, lsA, sb == qb1, tq1);
    }

    float liA = 1.0f / lsA, liB = 1.0f / lsB;
    float lrA[4], lrB[4];
    #pragma unroll
    for (int r = 0; r < 4; ++r) {
        lrA[r] = __shfl(liA, l4 * 4 + r, 64);
        lrB[r] = __shfl(liB, l4 * 4 + r, 64);
    }
    const int tA = t01 + w * 16 + l4 * 4;
    const int tB = t02 + w * 16 + l4 * 4;
    unsigned short* oa = o + ((size_t)(b * 768 + tA)) * 256 + h * 64;
    unsigned short* ob = o + ((size_t)(b * 768 + tB)) * 256 + h * 64;
    #pragma unroll
    for (int nf = 0; nf < 4; ++nf) {
        unsigned a01 = pk2bf(oA[nf][0] * lrA[0], oA[nf][1] * lrA[1]);
        unsigned a23 = pk2bf(oA[nf][2] * lrA[2], oA[nf][3] * lrA[3]);
        unsigned b01 = pk2bf(oB[nf][0] * lrB[0], oB[nf][1] * lrB[1]);
        unsigned b23 = pk2bf(oB[nf][2] * lrB[2], oB[nf][3] * lrB[3]);
        oa[nf * 16 + l15]       = (unsigned short)a01;
        oa[256 + nf * 16 + l15] = (unsigned short)(a01 >> 16);
        oa[512 + nf * 16 + l15] = (unsigned short)a23;
        oa[768 + nf * 16 + l15] = (unsigned short)(a23 >> 16);
        ob[nf * 16 + l15]       = (unsigned short)b01;
        ob[256 + nf * 16 + l15] = (unsigned short)(b01 >> 16);
        ob[512 + nf * 16 + l15] = (unsigned short)b23;
        ob[768 + nf * 16 + l15] = (unsigned short)(b23 >> 16);
    }
}

// ---------- launch ----------
extern "C" void kernel_launch(void* const* d_in, const int* in_sizes, int n_in,
                              void* d_out, int out_size, void* d_ws, size_t ws_size,
                              hipStream_t stream) {
    const float* x   = (const float*)d_in[0];
    const float* Wq  = (const float*)d_in[1];
    const float* Wk  = (const float*)d_in[2];
    const float* Wv  = (const float*)d_in[3];
    const float* Wo  = (const float*)d_in[4];
    const float* bo  = (const float*)d_in[5];
    const float* W1  = (const float*)d_in[6];
    const float* b1  = (const float*)d_in[7];
    const float* W2  = (const float*)d_in[8];
    const float* b2  = (const float*)d_in[9];
    const float* g1  = (const float*)d_in[10];
    const float* be1 = (const float*)d_in[11];
    const float* g2  = (const float*)d_in[12];
    const float* be2 = (const float*)d_in[13];

    char* ws = (char*)d_ws;
    unsigned short* qk_ws  = (unsigned short*)(ws + 0);          // 24576x512 bf16
    unsigned short* vT_ws  = (unsigned short*)(ws + 25165824);   // 256x24576 bf16
    unsigned short* o_ws   = (unsigned short*)(ws + 37748736);   // 24576x256 bf16
    unsigned short* h_ws   = (unsigned short*)(ws + 50331648);   // 24576x256 bf16 (LN1 out)
    unsigned short* x1b_ws = (unsigned short*)(ws + 62914560);   // 24576x256 bf16 residual
    unsigned short* wpackT = (unsigned short*)(ws + 88080384);   // 768x256 bf16
    unsigned short* woT    = (unsigned short*)(ws + 88473600);   // 256x256
    unsigned short* w1T    = (unsigned short*)(ws + 88604672);   // 1024x256
    unsigned short* w2T    = (unsigned short*)(ws + 89128960);   // 256x1024

    // transposes (192 blocks) + LN1 (6144 blocks)
    prep_k<<<6336, 256, 0, stream>>>(x, g1, be1, h_ws, Wq, Wk, Wv, Wo, W1, W2, wpackT, woT, w1T, w2T);
    // merged: QK [24576x512] (Q pre-scaled) + V^T [256x24576], XCD-grouped, counted-vmcnt dbuf
    qkv_k<<<1152, 256, 0, stream>>>(h_ws, wpackT, qk_ws, vT_ws);
    attn_k<<<768, 256, 0, stream>>>(qk_ws, vT_ws, o_ws);
    // O-proj + bo + resid(x, f32) -> x1 (bf16), counted-vmcnt dbuf
    oproj_k<<<dim3(2, 192), 256, 0, stream>>>(o_ws, woT, x1b_ws, bo, x);
    // fused LN2 + FF v9 (8 waves/block, counted-vmcnt): out = x1 + ReLU(LN2(x1)@W1+b1)@W2 + b2
    ff_fused<<<256, 512, 0, stream>>>(x1b_ws, g2, be2, w1T, w2T, b1, b2, (float*)d_out);
}